// Round 6
// baseline (274.620 us; speedup 1.0000x reference)
//
#include <hip/hip_runtime.h>
#include <math.h>

// AttentionSequencePoolingLayer (DIN), R6: MLP/occupancy round.
// R2 evidence: kernels sustain only ~1.8 TB/s (latency-bound staging chains,
// low occupancy), not BW-bound. Fixes: batched register loads before LDS
// writes (deep VMEM pipeline), gemm1 drops Ws LDS tile (B-frags from L2-hot
// global) -> 4 blocks/CU, gemm2 two-phase reduction (17KB LDS) -> 6 blocks/CU,
// attn 4x4 micro-tile transpose staging with b64 LDS writes.

typedef float f4 __attribute__((ext_vector_type(4)));
typedef float f32x4 __attribute__((ext_vector_type(4)));
typedef short s8v __attribute__((ext_vector_type(8)));
typedef short s4v __attribute__((ext_vector_type(4)));
typedef unsigned short u16;

#define B_   2048
#define T_   200
#define BT_  409600        // B_*T_
#define NB1  3200          // k_gemm1 blocks (128 rows each)
#define NB2  1600          // k_gemm2 blocks (256 rows each)

static __device__ __forceinline__ u16 f2bf(float f) {
  union { float f; unsigned u; } v; v.f = f;
  unsigned r = v.u + 0x7fffu + ((v.u >> 16) & 1u);   // RNE
  return (u16)(r >> 16);
}
static __device__ __forceinline__ float bf2f(u16 s) {
  union { unsigned u; float f; } v; v.u = ((unsigned)s) << 16;
  return v.f;
}

// ---------------- qW precompute + (blocks<32) W-prep
__global__ __launch_bounds__(256) void k_qw(
    const float* __restrict__ q, const float* __restrict__ W1,
    const float* __restrict__ b1, float* __restrict__ qW,
    u16* __restrict__ wsWT) {
  __shared__ float Wac[64 * 65];
  __shared__ float ql[16 * 64];
  const int tid = threadIdx.x;
#pragma unroll
  for (int i = 0; i < 16; i++) {
    int idx = tid + 256 * i;
    int k = idx >> 6, j = idx & 63;
    Wac[k * 65 + j] = W1[k * 64 + j] + W1[(128 + k) * 64 + j];
  }
  const int b0 = blockIdx.x * 16;
#pragma unroll
  for (int i = 0; i < 4; i++) {
    int idx = tid + 256 * i;
    ql[idx] = q[(size_t)b0 * 64 + idx];
  }
  __syncthreads();
  const int wv = tid >> 6, lane = tid & 63;
#pragma unroll
  for (int ii = 0; ii < 4; ii++) {
    const int bl = wv * 4 + ii;
    float acc = b1[lane];
#pragma unroll 8
    for (int k = 0; k < 64; k++) acc += ql[bl * 64 + k] * Wac[k * 65 + lane];
    qW[(size_t)(b0 + bl) * 64 + lane] = acc;
  }
  if (blockIdx.x < 32) {
    int t = blockIdx.x * 256 + tid;   // 8192 total
    int n = t >> 7, k = t & 127;
    float w = (k < 64) ? (W1[(64 + k) * 64 + n] - W1[(128 + k) * 64 + n])
                       : W1[(128 + k) * 64 + n];
    wsWT[t] = f2bf(w);
  }
}

// ---------------- K1: z1[BT][64](bf16) = [h | q*h](bf16) @ Wcomb(bf16) + qW; stats1
// 4 blocks/CU: LDS 35KB (no Ws tile; B-frags direct from L2-hot wsWT),
// hist loads batched into registers before conversion.
__global__ __launch_bounds__(256, 4) void k_gemm1(
    const float* __restrict__ q, const float* __restrict__ hist,
    const u16* __restrict__ wsWT, const float* __restrict__ qW,
    u16* __restrict__ z1, float* __restrict__ part1) {
  __shared__ __align__(16) u16 As[128 * 136];   // 34,816 B
  __shared__ __align__(16) float qs[256];       // q[bb0] | q[bb1] | qW[bb0] | qW[bb1]
  const int tid = threadIdx.x;
  const int R0 = blockIdx.x * 128;
  const int bb0 = (int)((unsigned)R0 / 200u);
  const int off0 = R0 - bb0 * 200;
  const int bb1 = (bb0 + 1 < B_) ? bb0 + 1 : B_ - 1;

  // pre-stage q + qW rows (2 batches each) into qs
  if (tid < 64) {
    int sel = tid >> 4, o4 = (tid & 15) * 4;
    const float* src = (sel < 2 ? q : qW) + (size_t)((sel & 1) ? bb1 : bb0) * 64 + o4;
    *(f4*)(qs + sel * 64 + o4) = *(const f4*)src;
  }
  // batched hist loads (independent, deep pipeline)
  f4 hreg[8];
#pragma unroll
  for (int i = 0; i < 8; i++) {
    int piece = tid + 256 * i;               // 2048 pieces of 4 floats
    int row = piece >> 4, c4 = piece & 15;
    hreg[i] = *(const f4*)(hist + (size_t)(R0 + row) * 64 + 4 * c4);
  }
  __syncthreads();   // qs ready (barrier also drains hreg loads)

  // convert + write As: cols 0..63 = h, 64..127 = q*h
#pragma unroll
  for (int i = 0; i < 8; i++) {
    int piece = tid + 256 * i;
    int row = piece >> 4, c4 = piece & 15;
    int bsel = (off0 + row) >= 200;
    f4 h4 = hreg[i];
    f4 q4 = *(const f4*)(qs + bsel * 64 + 4 * c4);
    f4 p4 = h4 * q4;
    s4v hv, pv;
#pragma unroll
    for (int j = 0; j < 4; j++) { hv[j] = (short)f2bf(h4[j]); pv[j] = (short)f2bf(p4[j]); }
    *(s4v*)(As + row * 136 + 4 * c4) = hv;
    *(s4v*)(As + row * 136 + 64 + 4 * c4) = pv;
  }
  __syncthreads();

  const int wv = tid >> 6, lane = tid & 63;
  const int lm16 = lane & 15, quad = lane >> 4;
  f32x4 acc[2][4];
#pragma unroll
  for (int mt = 0; mt < 2; mt++)
#pragma unroll
    for (int nt = 0; nt < 4; nt++) acc[mt][nt] = (f32x4)0.f;

#pragma unroll
  for (int c = 0; c < 4; c++) {
    const int ko = 32 * c + 8 * quad;
    s8v a0 = *(const s8v*)(As + (32 * wv + lm16) * 136 + ko);
    s8v a1 = *(const s8v*)(As + (32 * wv + 16 + lm16) * 136 + ko);
#pragma unroll
    for (int nt = 0; nt < 4; nt++) {
      s8v b8 = *(const s8v*)(wsWT + (16 * nt + lm16) * 128 + ko);  // L2-hot
      acc[0][nt] = __builtin_amdgcn_mfma_f32_16x16x32_bf16(a0, b8, acc[0][nt], 0, 0, 0);
      acc[1][nt] = __builtin_amdgcn_mfma_f32_16x16x32_bf16(a1, b8, acc[1][nt], 0, 0, 0);
    }
  }
  __syncthreads();

  // epilogue: qW bias from LDS, stats, bf16 repack via LDS (reuse As)
  u16* zs = As;                               // [128][72] bf16 = 18,432 B
  float* red = (float*)(As + 128 * 72);       // 2048 floats = 8 KB (fits in As)
  const int g = wv * 4 + quad;
  float s[4] = {0.f, 0.f, 0.f, 0.f}, sq[4] = {0.f, 0.f, 0.f, 0.f};
#pragma unroll
  for (int mt = 0; mt < 2; mt++)
#pragma unroll
    for (int nt = 0; nt < 4; nt++)
#pragma unroll
      for (int r = 0; r < 4; r++) {
        int row = 32 * wv + 16 * mt + 4 * quad + r;
        int bsel = (off0 + row) >= 200;
        int col = 16 * nt + lm16;
        float v = acc[mt][nt][r] + qs[128 + bsel * 64 + col];
        s[nt] += v; sq[nt] += v * v;
        zs[row * 72 + col] = f2bf(v);
      }
#pragma unroll
  for (int nt = 0; nt < 4; nt++) {
    red[g * 64 + 16 * nt + lm16] = s[nt];
    red[1024 + g * 64 + 16 * nt + lm16] = sq[nt];
  }
  __syncthreads();
#pragma unroll
  for (int i = 0; i < 4; i++) {
    int piece = tid + 256 * i;               // 1024 pieces of 8 bf16
    int row = piece >> 3, seg = piece & 7;
    s8v v = *(const s8v*)(zs + row * 72 + 8 * seg);
    *(s8v*)(z1 + (size_t)(R0 + row) * 64 + 8 * seg) = v;
  }
  if (tid < 64) {
    float ss = 0.f, qq = 0.f;
#pragma unroll
    for (int gg = 0; gg < 16; gg++) { ss += red[gg * 64 + tid]; qq += red[1024 + gg * 64 + tid]; }
    part1[(size_t)blockIdx.x * 128 + tid] = ss;
    part1[(size_t)blockIdx.x * 128 + 64 + tid] = qq;
  }
}

// ---------------- finalize: mean/rstd per feature from [block][feature] partials
__global__ __launch_bounds__(256) void k_finalize(
    const float* __restrict__ part, float* __restrict__ statout,
    int nj, int stride, int nb, float invN) {
  const int j = blockIdx.x, tid = threadIdx.x;
  float s = 0.f, qq = 0.f;
  for (int i = tid; i < nb; i += 256) {
    s += part[(size_t)i * stride + j];
    qq += part[(size_t)i * stride + nj + j];
  }
#pragma unroll
  for (int off = 32; off > 0; off >>= 1) {
    s += __shfl_down(s, off);
    qq += __shfl_down(qq, off);
  }
  __shared__ float rs[4], rq[4];
  if ((tid & 63) == 0) { rs[tid >> 6] = s; rq[tid >> 6] = qq; }
  __syncthreads();
  if (tid == 0) {
    s = rs[0] + rs[1] + rs[2] + rs[3];
    qq = rq[0] + rq[1] + rq[2] + rq[3];
    float mean = s * invN;
    float var = qq * invN - mean * mean;
    statout[j] = mean;
    statout[nj + j] = rsqrtf(var + 1e-8f);
  }
}

// ---------------- K2: h = dice1(z1 bf16); z2(bf16) = h @ W2 + b2; stats2
// batched z1 loads; two-phase 17KB reduction buffer -> ~6 blocks/CU
__global__ __launch_bounds__(256, 6) void k_gemm2(
    const u16* __restrict__ z1, const float* __restrict__ W2g,
    const float* __restrict__ b2, const float* __restrict__ alpha1,
    const float* __restrict__ stat1, u16* __restrict__ z2,
    float* __restrict__ part2) {
  __shared__ float W2l[64 * 16];
  __shared__ float cf[208];        // mean[64], rstd[64], alpha[64], b2[16]
  __shared__ float red[256 * 17];  // 17,408 B
  const int tid = threadIdx.x;
  if (tid < 64) {
    cf[tid] = stat1[tid];
    cf[64 + tid] = stat1[64 + tid];
    cf[128 + tid] = alpha1[tid];
  }
  if (tid < 16) cf[192 + tid] = b2[tid];
#pragma unroll
  for (int i = 0; i < 4; i++) { int idx = tid + 256 * i; W2l[idx] = W2g[idx]; }
  const size_t row = (size_t)blockIdx.x * 256 + tid;
  const u16* zr = z1 + row * 64;
  s8v xv[8];
#pragma unroll
  for (int i = 0; i < 8; i++) xv[i] = *(const s8v*)(zr + 8 * i);  // batched
  __syncthreads();
  float acc[16];
#pragma unroll
  for (int j = 0; j < 16; j++) acc[j] = cf[192 + j];
#pragma unroll
  for (int i = 0; i < 8; i++) {
#pragma unroll
    for (int dk = 0; dk < 8; dk++) {
      int k = 8 * i + dk;
      float x = bf2f((u16)xv[i][dk]);
      float xn = (x - cf[k]) * cf[64 + k];
      float p = 1.f / (1.f + __expf(-xn));
      float h = x * (p + (1.f - p) * cf[128 + k]);
#pragma unroll
      for (int jc = 0; jc < 4; jc++) {
        f4 w = *(const f4*)(W2l + k * 16 + 4 * jc);
#pragma unroll
        for (int jj = 0; jj < 4; jj++) acc[4 * jc + jj] += h * w[jj];
      }
    }
  }
  s8v o0, o1;
#pragma unroll
  for (int jj = 0; jj < 8; jj++) { o0[jj] = (short)f2bf(acc[jj]); o1[jj] = (short)f2bf(acc[8 + jj]); }
  *(s8v*)(z2 + row * 16) = o0;
  *(s8v*)(z2 + row * 16 + 8) = o1;
  // phase 1: sums
#pragma unroll
  for (int j = 0; j < 16; j++) red[tid * 17 + j] = acc[j];
  __syncthreads();
  {
    const int f = tid >> 4, sub = tid & 15;
    float s = 0.f;
#pragma unroll
    for (int i = 0; i < 16; i++) s += red[(sub + 16 * i) * 17 + f];
    s += __shfl_down(s, 8, 16);
    s += __shfl_down(s, 4, 16);
    s += __shfl_down(s, 2, 16);
    s += __shfl_down(s, 1, 16);
    if (sub == 0) part2[(size_t)blockIdx.x * 32 + f] = s;
  }
  __syncthreads();
  // phase 2: sumsqs
#pragma unroll
  for (int j = 0; j < 16; j++) red[tid * 17 + j] = acc[j] * acc[j];
  __syncthreads();
  {
    const int f = tid >> 4, sub = tid & 15;
    float s = 0.f;
#pragma unroll
    for (int i = 0; i < 16; i++) s += red[(sub + 16 * i) * 17 + f];
    s += __shfl_down(s, 8, 16);
    s += __shfl_down(s, 4, 16);
    s += __shfl_down(s, 2, 16);
    s += __shfl_down(s, 1, 16);
    if (sub == 0) part2[(size_t)blockIdx.x * 32 + 16 + f] = s;
  }
}

// ---------------- K3: dice2(z2 bf16) -> inverted-mask softmax -> MFMA score@hist
__global__ __launch_bounds__(256, 3) void k_attn(
    const float* __restrict__ hist, const u16* __restrict__ z2,
    const int* __restrict__ lens, const float* __restrict__ alpha2,
    const float* __restrict__ stat2, float* __restrict__ out) {
  __shared__ float lm[200 * 17];                 // masked logits [t][h]
  __shared__ __align__(16) u16 scb[16 * 232];    // score bf16 [h][t], K-padded 224
  __shared__ __align__(16) u16 hT[64 * 232];     // hist^T bf16 [e][t]
  __shared__ float cf2[48];
  const int tid = threadIdx.x;
  const int b = blockIdx.x;
  const int L = lens[b];
  if (tid < 16) {
    cf2[tid] = stat2[tid];
    cf2[16 + tid] = stat2[16 + tid];
    cf2[32 + tid] = alpha2[tid];
  }
  // clear K-pad cols t=200..231: 64 scb chunks + 256 hT chunks = 320 total
  {
    s8v zz = {0, 0, 0, 0, 0, 0, 0, 0};
    for (int p = tid; p < 320; p += 256) {
      if (p < 64) { int r = p >> 2, c = p & 3; *(s8v*)(scb + r * 232 + 200 + 8 * c) = zz; }
      else { int pp = p - 64; int r = pp >> 2, c = pp & 3; *(s8v*)(hT + r * 232 + 200 + 8 * c) = zz; }
    }
  }
  // stage hist -> hT transposed bf16: 4x4 micro-tiles, batched f4 loads, b64 writes
  const float* hb = hist + (size_t)b * 200 * 64;
#pragma unroll
  for (int l = 0; l < 4; l++) {
    int p = tid + 256 * l;                     // 800 tasks (50 t-groups x 16 e-groups)
    if (p < 800) {
      int tg = p >> 4, eg = p & 15;
      int t0 = 4 * tg, e0 = 4 * eg;
      f4 r0 = *(const f4*)(hb + (size_t)(t0 + 0) * 64 + e0);
      f4 r1 = *(const f4*)(hb + (size_t)(t0 + 1) * 64 + e0);
      f4 r2 = *(const f4*)(hb + (size_t)(t0 + 2) * 64 + e0);
      f4 r3 = *(const f4*)(hb + (size_t)(t0 + 3) * 64 + e0);
#pragma unroll
      for (int j = 0; j < 4; j++) {
        s4v sv;
        sv[0] = (short)f2bf(r0[j]); sv[1] = (short)f2bf(r1[j]);
        sv[2] = (short)f2bf(r2[j]); sv[3] = (short)f2bf(r3[j]);
        *(s4v*)(hT + (e0 + j) * 232 + t0) = sv;
      }
    }
  }
  // dice2 + inverted mask -> lm
  if (tid < 200) {
    const u16* zr = z2 + ((size_t)b * 200 + tid) * 16;
    s8v x0 = *(const s8v*)zr, x1 = *(const s8v*)(zr + 8);
#pragma unroll
    for (int j = 0; j < 16; j++) {
      float x = bf2f((u16)(j < 8 ? x0[j] : x1[j - 8]));
      float xn = (x - cf2[j]) * cf2[16 + j];
      float p = 1.f / (1.f + __expf(-xn));
      float lg = x * (p + (1.f - p) * cf2[32 + j]);
      lm[tid * 17 + j] = (tid < L) ? 1e-9f : lg;   // reference: where(t<len, 1e-9, logits)
    }
  }
  __syncthreads();
  // softmax per h over t (16-lane teams), write bf16 scores
  {
    const int h = tid >> 4, s = tid & 15;
    float v[13];
    float m = -1e30f;
#pragma unroll
    for (int i = 0; i < 13; i++) {
      int t = s + 16 * i;
      float x = (t < 200) ? lm[t * 17 + h] : -1e30f;
      v[i] = x;
      m = fmaxf(m, x);
    }
#pragma unroll
    for (int mk = 8; mk > 0; mk >>= 1) m = fmaxf(m, __shfl_xor(m, mk, 16));
    float sum = 0.f;
#pragma unroll
    for (int i = 0; i < 13; i++) {
      int t = s + 16 * i;
      if (t < 200) { float e = __expf(v[i] - m); v[i] = e; sum += e; }
    }
#pragma unroll
    for (int mk = 8; mk > 0; mk >>= 1) sum += __shfl_xor(sum, mk, 16);
    const float inv = 1.f / sum;
#pragma unroll
    for (int i = 0; i < 13; i++) {
      int t = s + 16 * i;
      if (t < 200) scb[h * 232 + t] = f2bf(v[i] * inv);
    }
  }
  __syncthreads();
  // MFMA: out[16,64] = score[16,224] @ hist[224,64]; wave wv owns e-block 16*wv
  {
    const int wv = tid >> 6, lane = tid & 63;
    const int lm16 = lane & 15, quad = lane >> 4;
    f32x4 acc = {0.f, 0.f, 0.f, 0.f};
#pragma unroll
    for (int c = 0; c < 7; c++) {
      const int ko = 32 * c + 8 * quad;
      s8v a = *(const s8v*)(scb + lm16 * 232 + ko);
      s8v bb = *(const s8v*)(hT + (16 * wv + lm16) * 232 + ko);
      acc = __builtin_amdgcn_mfma_f32_16x16x32_bf16(a, bb, acc, 0, 0, 0);
    }
#pragma unroll
    for (int r = 0; r < 4; r++) {
      int h = 4 * quad + r;
      out[(size_t)b * 1024 + h * 64 + 16 * wv + lm16] = acc[r];
    }
  }
}

extern "C" void kernel_launch(void* const* d_in, const int* in_sizes, int n_in,
                              void* d_out, int out_size, void* d_ws, size_t ws_size,
                              hipStream_t stream) {
  const float* q    = (const float*)d_in[0];
  const float* hist = (const float*)d_in[1];
  const int*   len  = (const int*)d_in[2];
  const float* W1   = (const float*)d_in[3];
  const float* b1   = (const float*)d_in[4];
  const float* al1  = (const float*)d_in[5];
  const float* W2   = (const float*)d_in[6];
  const float* b2   = (const float*)d_in[7];
  const float* al2  = (const float*)d_in[8];
  float* out = (float*)d_out;

  // ws layout (bytes): z1(bf16) | z2(bf16) | qW(f32) | wsWT(bf16) | part1 | part2
  char* ws = (char*)d_ws;
  u16*   z1    = (u16*)ws;                                   // 52,428,800 B
  u16*   z2    = (u16*)(ws + 52428800);                      // 13,107,200 B
  float* qW    = (float*)(ws + 52428800 + 13107200);         //    524,288 B
  u16*   wsWT  = (u16*)((char*)qW + 524288);                 //     16,384 B
  float* part1 = (float*)((char*)wsWT + 16384);              //  1,638,400 B
  float* part2 = part1 + (size_t)NB1 * 128;                  //    204,800 B
  float* stat1 = part2 + (size_t)NB2 * 32;                   //        512 B
  float* stat2 = stat1 + 128;                                //        128 B
  (void)ws_size; (void)in_sizes; (void)n_in; (void)out_size;

  k_qw<<<dim3(128), dim3(256), 0, stream>>>(q, W1, b1, qW, wsWT);
  k_gemm1<<<dim3(NB1), dim3(256), 0, stream>>>(q, hist, wsWT, qW, z1, part1);
  k_finalize<<<dim3(64), dim3(256), 0, stream>>>(part1, stat1, 64, 128, NB1, 1.f / (float)BT_);
  k_gemm2<<<dim3(NB2), dim3(256), 0, stream>>>(z1, W2, b2, al1, stat1, z2, part2);
  k_finalize<<<dim3(16), dim3(256), 0, stream>>>(part2, stat2, 16, 32, NB2, 1.f / (float)BT_);
  k_attn<<<dim3(B_), dim3(256), 0, stream>>>(hist, z2, len, al2, stat2, out);
}

// Round 8
// 252.219 us; speedup vs baseline: 1.0888x; 1.0888x over previous
//
#include <hip/hip_runtime.h>
#include <math.h>

// AttentionSequencePoolingLayer (DIN), R8: recovery round — best validated assembly.
// R6 regressed (gemm1 rewrite: 70us), R7 broke (absmax 3.17, unlocalizable without
// profile). Lesson: one structural change per round. This source = R4b gemm1
// (validated 255us run) + R6 gemm2 (two-phase) + R6 attn (micro-tile staging),
// all from PASSING runs, zero new experiments.

typedef float f4 __attribute__((ext_vector_type(4)));
typedef float f32x4 __attribute__((ext_vector_type(4)));
typedef short s8v __attribute__((ext_vector_type(8)));
typedef short s4v __attribute__((ext_vector_type(4)));
typedef unsigned short u16;

#define B_   2048
#define T_   200
#define BT_  409600        // B_*T_
#define NB1  3200          // k_gemm1 blocks (128 rows each)
#define NB2  1600          // k_gemm2 blocks (256 rows each)

static __device__ __forceinline__ u16 f2bf(float f) {
  union { float f; unsigned u; } v; v.f = f;
  unsigned r = v.u + 0x7fffu + ((v.u >> 16) & 1u);   // RNE
  return (u16)(r >> 16);
}
static __device__ __forceinline__ float bf2f(u16 s) {
  union { unsigned u; float f; } v; v.u = ((unsigned)s) << 16;
  return v.f;
}

// ---------------- qW precompute + (blocks<32) W-prep
// qW[b][j] = b1[j] + sum_k q[b][k]*(W1[k][j]+W1[128+k][j])
// wsWT[n][k] = Wcomb[k][n] bf16, Wcomb = [Wb-Wc ; Wd]
__global__ __launch_bounds__(256) void k_qw(
    const float* __restrict__ q, const float* __restrict__ W1,
    const float* __restrict__ b1, float* __restrict__ qW,
    u16* __restrict__ wsWT) {
  __shared__ float Wac[64 * 65];
  __shared__ float ql[16 * 64];
  const int tid = threadIdx.x;
#pragma unroll
  for (int i = 0; i < 16; i++) {
    int idx = tid + 256 * i;
    int k = idx >> 6, j = idx & 63;
    Wac[k * 65 + j] = W1[k * 64 + j] + W1[(128 + k) * 64 + j];
  }
  const int b0 = blockIdx.x * 16;
#pragma unroll
  for (int i = 0; i < 4; i++) {
    int idx = tid + 256 * i;
    ql[idx] = q[(size_t)b0 * 64 + idx];
  }
  __syncthreads();
  const int wv = tid >> 6, lane = tid & 63;
#pragma unroll
  for (int ii = 0; ii < 4; ii++) {
    const int bl = wv * 4 + ii;
    float acc = b1[lane];
#pragma unroll 8
    for (int k = 0; k < 64; k++) acc += ql[bl * 64 + k] * Wac[k * 65 + lane];
    qW[(size_t)(b0 + bl) * 64 + lane] = acc;
  }
  if (blockIdx.x < 32) {
    int t = blockIdx.x * 256 + tid;   // 8192 total
    int n = t >> 7, k = t & 127;
    float w = (k < 64) ? (W1[(64 + k) * 64 + n] - W1[(128 + k) * 64 + n])
                       : W1[(128 + k) * 64 + n];
    wsWT[t] = f2bf(w);
  }
}

// ---------------- K1: z1[BT][64](bf16) = [h | q*h](bf16) @ Wcomb(bf16) + qW; stats1
// R4b-validated: 128-row tile, LDS-staged A and Ws, (256,3).
__global__ __launch_bounds__(256, 3) void k_gemm1(
    const float* __restrict__ q, const float* __restrict__ hist,
    const u16* __restrict__ wsWT, const float* __restrict__ qW,
    u16* __restrict__ z1, float* __restrict__ part1) {
  __shared__ __align__(16) u16 As[128 * 136];
  __shared__ __align__(16) u16 Ws[64 * 136];
  const int tid = threadIdx.x;
  const int R0 = blockIdx.x * 128;

#pragma unroll
  for (int i = 0; i < 4; i++) {
    int piece = tid + 256 * i;               // 1024 pieces of 8 bf16
    int n = piece >> 4, k8 = piece & 15;
    *(s8v*)(Ws + n * 136 + 8 * k8) = *(const s8v*)(wsWT + n * 128 + 8 * k8);
  }
#pragma unroll
  for (int i = 0; i < 8; i++) {
    int piece = tid + 256 * i;               // 2048 pieces of 4 floats
    int row = piece >> 4, c4 = piece & 15;
    int R = R0 + row;
    int b = (int)((unsigned)R / 200u);
    f4 h4 = *(const f4*)(hist + (size_t)R * 64 + 4 * c4);
    f4 q4 = *(const f4*)(q + (size_t)b * 64 + 4 * c4);
    f4 p4 = h4 * q4;
    s4v hv, pv;
#pragma unroll
    for (int j = 0; j < 4; j++) { hv[j] = (short)f2bf(h4[j]); pv[j] = (short)f2bf(p4[j]); }
    *(s4v*)(As + row * 136 + 4 * c4) = hv;
    *(s4v*)(As + row * 136 + 64 + 4 * c4) = pv;
  }
  __syncthreads();

  const int wv = tid >> 6, lane = tid & 63;
  const int lm16 = lane & 15, quad = lane >> 4;
  f32x4 acc[2][4];
#pragma unroll
  for (int mt = 0; mt < 2; mt++)
#pragma unroll
    for (int nt = 0; nt < 4; nt++) acc[mt][nt] = (f32x4)0.f;

#pragma unroll
  for (int c = 0; c < 4; c++) {
    const int ko = 32 * c + 8 * quad;
    s8v a0 = *(const s8v*)(As + (32 * wv + lm16) * 136 + ko);
    s8v a1 = *(const s8v*)(As + (32 * wv + 16 + lm16) * 136 + ko);
#pragma unroll
    for (int nt = 0; nt < 4; nt++) {
      s8v b8 = *(const s8v*)(Ws + (16 * nt + lm16) * 136 + ko);
      acc[0][nt] = __builtin_amdgcn_mfma_f32_16x16x32_bf16(a0, b8, acc[0][nt], 0, 0, 0);
      acc[1][nt] = __builtin_amdgcn_mfma_f32_16x16x32_bf16(a1, b8, acc[1][nt], 0, 0, 0);
    }
  }
  __syncthreads();

  u16* zs = As;                 // [128][72] bf16
  float* red = (float*)Ws;      // red_s[16][64] | red_q[16][64]
  const int g = wv * 4 + quad;
  float s[4] = {0.f, 0.f, 0.f, 0.f}, sq[4] = {0.f, 0.f, 0.f, 0.f};
#pragma unroll
  for (int mt = 0; mt < 2; mt++)
#pragma unroll
    for (int nt = 0; nt < 4; nt++)
#pragma unroll
      for (int r = 0; r < 4; r++) {
        int row = 32 * wv + 16 * mt + 4 * quad + r;
        int R = R0 + row;
        int b = (int)((unsigned)R / 200u);
        int col = 16 * nt + lm16;
        float v = acc[mt][nt][r] + qW[(size_t)b * 64 + col];
        s[nt] += v; sq[nt] += v * v;
        zs[row * 72 + col] = f2bf(v);
      }
#pragma unroll
  for (int nt = 0; nt < 4; nt++) {
    red[g * 64 + 16 * nt + lm16] = s[nt];
    red[1024 + g * 64 + 16 * nt + lm16] = sq[nt];
  }
  __syncthreads();
#pragma unroll
  for (int i = 0; i < 4; i++) {
    int piece = tid + 256 * i;               // 1024 pieces of 8 bf16
    int row = piece >> 3, seg = piece & 7;
    s8v v = *(const s8v*)(zs + row * 72 + 8 * seg);
    *(s8v*)(z1 + (size_t)(R0 + row) * 64 + 8 * seg) = v;
  }
  if (tid < 64) {
    float ss = 0.f, qq = 0.f;
#pragma unroll
    for (int gg = 0; gg < 16; gg++) { ss += red[gg * 64 + tid]; qq += red[1024 + gg * 64 + tid]; }
    part1[(size_t)blockIdx.x * 128 + tid] = ss;
    part1[(size_t)blockIdx.x * 128 + 64 + tid] = qq;
  }
}

// ---------------- finalize: mean/rstd per feature from [block][feature] partials
__global__ __launch_bounds__(256) void k_finalize(
    const float* __restrict__ part, float* __restrict__ statout,
    int nj, int stride, int nb, float invN) {
  const int j = blockIdx.x, tid = threadIdx.x;
  float s = 0.f, qq = 0.f;
  for (int i = tid; i < nb; i += 256) {
    s += part[(size_t)i * stride + j];
    qq += part[(size_t)i * stride + nj + j];
  }
#pragma unroll
  for (int off = 32; off > 0; off >>= 1) {
    s += __shfl_down(s, off);
    qq += __shfl_down(qq, off);
  }
  __shared__ float rs[4], rq[4];
  if ((tid & 63) == 0) { rs[tid >> 6] = s; rq[tid >> 6] = qq; }
  __syncthreads();
  if (tid == 0) {
    s = rs[0] + rs[1] + rs[2] + rs[3];
    qq = rq[0] + rq[1] + rq[2] + rq[3];
    float mean = s * invN;
    float var = qq * invN - mean * mean;
    statout[j] = mean;
    statout[nj + j] = rsqrtf(var + 1e-8f);
  }
}

// ---------------- K2: h = dice1(z1 bf16); z2(bf16) = h @ W2 + b2; stats2
// R6-validated: batched z1 loads, two-phase 17KB reduction, (256,6).
__global__ __launch_bounds__(256, 6) void k_gemm2(
    const u16* __restrict__ z1, const float* __restrict__ W2g,
    const float* __restrict__ b2, const float* __restrict__ alpha1,
    const float* __restrict__ stat1, u16* __restrict__ z2,
    float* __restrict__ part2) {
  __shared__ float W2l[64 * 16];
  __shared__ float cf[208];        // mean[64], rstd[64], alpha[64], b2[16]
  __shared__ float red[256 * 17];  // 17,408 B
  const int tid = threadIdx.x;
  if (tid < 64) {
    cf[tid] = stat1[tid];
    cf[64 + tid] = stat1[64 + tid];
    cf[128 + tid] = alpha1[tid];
  }
  if (tid < 16) cf[192 + tid] = b2[tid];
#pragma unroll
  for (int i = 0; i < 4; i++) { int idx = tid + 256 * i; W2l[idx] = W2g[idx]; }
  const size_t row = (size_t)blockIdx.x * 256 + tid;
  const u16* zr = z1 + row * 64;
  s8v xv[8];
#pragma unroll
  for (int i = 0; i < 8; i++) xv[i] = *(const s8v*)(zr + 8 * i);  // batched
  __syncthreads();
  float acc[16];
#pragma unroll
  for (int j = 0; j < 16; j++) acc[j] = cf[192 + j];
#pragma unroll
  for (int i = 0; i < 8; i++) {
#pragma unroll
    for (int dk = 0; dk < 8; dk++) {
      int k = 8 * i + dk;
      float x = bf2f((u16)xv[i][dk]);
      float xn = (x - cf[k]) * cf[64 + k];
      float p = 1.f / (1.f + __expf(-xn));
      float h = x * (p + (1.f - p) * cf[128 + k]);
#pragma unroll
      for (int jc = 0; jc < 4; jc++) {
        f4 w = *(const f4*)(W2l + k * 16 + 4 * jc);
#pragma unroll
        for (int jj = 0; jj < 4; jj++) acc[4 * jc + jj] += h * w[jj];
      }
    }
  }
  s8v o0, o1;
#pragma unroll
  for (int jj = 0; jj < 8; jj++) { o0[jj] = (short)f2bf(acc[jj]); o1[jj] = (short)f2bf(acc[8 + jj]); }
  *(s8v*)(z2 + row * 16) = o0;
  *(s8v*)(z2 + row * 16 + 8) = o1;
  // phase 1: sums
#pragma unroll
  for (int j = 0; j < 16; j++) red[tid * 17 + j] = acc[j];
  __syncthreads();
  {
    const int f = tid >> 4, sub = tid & 15;
    float s = 0.f;
#pragma unroll
    for (int i = 0; i < 16; i++) s += red[(sub + 16 * i) * 17 + f];
    s += __shfl_down(s, 8, 16);
    s += __shfl_down(s, 4, 16);
    s += __shfl_down(s, 2, 16);
    s += __shfl_down(s, 1, 16);
    if (sub == 0) part2[(size_t)blockIdx.x * 32 + f] = s;
  }
  __syncthreads();
  // phase 2: sumsqs
#pragma unroll
  for (int j = 0; j < 16; j++) red[tid * 17 + j] = acc[j] * acc[j];
  __syncthreads();
  {
    const int f = tid >> 4, sub = tid & 15;
    float s = 0.f;
#pragma unroll
    for (int i = 0; i < 16; i++) s += red[(sub + 16 * i) * 17 + f];
    s += __shfl_down(s, 8, 16);
    s += __shfl_down(s, 4, 16);
    s += __shfl_down(s, 2, 16);
    s += __shfl_down(s, 1, 16);
    if (sub == 0) part2[(size_t)blockIdx.x * 32 + 16 + f] = s;
  }
}

// ---------------- K3: dice2(z2 bf16) -> inverted-mask softmax -> MFMA score@hist
// R6-validated: micro-tile transpose staging, strided pad clear, (256,3).
__global__ __launch_bounds__(256, 3) void k_attn(
    const float* __restrict__ hist, const u16* __restrict__ z2,
    const int* __restrict__ lens, const float* __restrict__ alpha2,
    const float* __restrict__ stat2, float* __restrict__ out) {
  __shared__ float lm[200 * 17];                 // masked logits [t][h]
  __shared__ __align__(16) u16 scb[16 * 232];    // score bf16 [h][t], K-padded 224
  __shared__ __align__(16) u16 hT[64 * 232];     // hist^T bf16 [e][t]
  __shared__ float cf2[48];
  const int tid = threadIdx.x;
  const int b = blockIdx.x;
  const int L = lens[b];
  if (tid < 16) {
    cf2[tid] = stat2[tid];
    cf2[16 + tid] = stat2[16 + tid];
    cf2[32 + tid] = alpha2[tid];
  }
  // clear K-pad cols t=200..231: 64 scb chunks + 256 hT chunks = 320 total
  {
    s8v zz = {0, 0, 0, 0, 0, 0, 0, 0};
    for (int p = tid; p < 320; p += 256) {
      if (p < 64) { int r = p >> 2, c = p & 3; *(s8v*)(scb + r * 232 + 200 + 8 * c) = zz; }
      else { int pp = p - 64; int r = pp >> 2, c = pp & 3; *(s8v*)(hT + r * 232 + 200 + 8 * c) = zz; }
    }
  }
  // stage hist -> hT transposed bf16: 4x4 micro-tiles, batched f4 loads, b64 writes
  const float* hb = hist + (size_t)b * 200 * 64;
#pragma unroll
  for (int l = 0; l < 4; l++) {
    int p = tid + 256 * l;                     // 800 tasks (50 t-groups x 16 e-groups)
    if (p < 800) {
      int tg = p >> 4, eg = p & 15;
      int t0 = 4 * tg, e0 = 4 * eg;
      f4 r0 = *(const f4*)(hb + (size_t)(t0 + 0) * 64 + e0);
      f4 r1 = *(const f4*)(hb + (size_t)(t0 + 1) * 64 + e0);
      f4 r2 = *(const f4*)(hb + (size_t)(t0 + 2) * 64 + e0);
      f4 r3 = *(const f4*)(hb + (size_t)(t0 + 3) * 64 + e0);
#pragma unroll
      for (int j = 0; j < 4; j++) {
        s4v sv;
        sv[0] = (short)f2bf(r0[j]); sv[1] = (short)f2bf(r1[j]);
        sv[2] = (short)f2bf(r2[j]); sv[3] = (short)f2bf(r3[j]);
        *(s4v*)(hT + (e0 + j) * 232 + t0) = sv;
      }
    }
  }
  // dice2 + inverted mask -> lm
  if (tid < 200) {
    const u16* zr = z2 + ((size_t)b * 200 + tid) * 16;
    s8v x0 = *(const s8v*)zr, x1 = *(const s8v*)(zr + 8);
#pragma unroll
    for (int j = 0; j < 16; j++) {
      float x = bf2f((u16)(j < 8 ? x0[j] : x1[j - 8]));
      float xn = (x - cf2[j]) * cf2[16 + j];
      float p = 1.f / (1.f + __expf(-xn));
      float lg = x * (p + (1.f - p) * cf2[32 + j]);
      lm[tid * 17 + j] = (tid < L) ? 1e-9f : lg;   // reference: where(t<len, 1e-9, logits)
    }
  }
  __syncthreads();
  // softmax per h over t (16-lane teams), write bf16 scores
  {
    const int h = tid >> 4, s = tid & 15;
    float v[13];
    float m = -1e30f;
#pragma unroll
    for (int i = 0; i < 13; i++) {
      int t = s + 16 * i;
      float x = (t < 200) ? lm[t * 17 + h] : -1e30f;
      v[i] = x;
      m = fmaxf(m, x);
    }
#pragma unroll
    for (int mk = 8; mk > 0; mk >>= 1) m = fmaxf(m, __shfl_xor(m, mk, 16));
    float sum = 0.f;
#pragma unroll
    for (int i = 0; i < 13; i++) {
      int t = s + 16 * i;
      if (t < 200) { float e = __expf(v[i] - m); v[i] = e; sum += e; }
    }
#pragma unroll
    for (int mk = 8; mk > 0; mk >>= 1) sum += __shfl_xor(sum, mk, 16);
    const float inv = 1.f / sum;
#pragma unroll
    for (int i = 0; i < 13; i++) {
      int t = s + 16 * i;
      if (t < 200) scb[h * 232 + t] = f2bf(v[i] * inv);
    }
  }
  __syncthreads();
  // MFMA: out[16,64] = score[16,224] @ hist[224,64]; wave wv owns e-block 16*wv
  {
    const int wv = tid >> 6, lane = tid & 63;
    const int lm16 = lane & 15, quad = lane >> 4;
    f32x4 acc = {0.f, 0.f, 0.f, 0.f};
#pragma unroll
    for (int c = 0; c < 7; c++) {
      const int ko = 32 * c + 8 * quad;
      s8v a = *(const s8v*)(scb + lm16 * 232 + ko);
      s8v bb = *(const s8v*)(hT + (16 * wv + lm16) * 232 + ko);
      acc = __builtin_amdgcn_mfma_f32_16x16x32_bf16(a, bb, acc, 0, 0, 0);
    }
#pragma unroll
    for (int r = 0; r < 4; r++) {
      int h = 4 * quad + r;
      out[(size_t)b * 1024 + h * 64 + 16 * wv + lm16] = acc[r];
    }
  }
}

extern "C" void kernel_launch(void* const* d_in, const int* in_sizes, int n_in,
                              void* d_out, int out_size, void* d_ws, size_t ws_size,
                              hipStream_t stream) {
  const float* q    = (const float*)d_in[0];
  const float* hist = (const float*)d_in[1];
  const int*   len  = (const int*)d_in[2];
  const float* W1   = (const float*)d_in[3];
  const float* b1   = (const float*)d_in[4];
  const float* al1  = (const float*)d_in[5];
  const float* W2   = (const float*)d_in[6];
  const float* b2   = (const float*)d_in[7];
  const float* al2  = (const float*)d_in[8];
  float* out = (float*)d_out;

  // ws layout (bytes): z1(bf16) | z2(bf16) | qW(f32) | wsWT(bf16) | part1 | part2
  char* ws = (char*)d_ws;
  u16*   z1    = (u16*)ws;                                   // 52,428,800 B
  u16*   z2    = (u16*)(ws + 52428800);                      // 13,107,200 B
  float* qW    = (float*)(ws + 52428800 + 13107200);         //    524,288 B
  u16*   wsWT  = (u16*)((char*)qW + 524288);                 //     16,384 B
  float* part1 = (float*)((char*)wsWT + 16384);              //  1,638,400 B
  float* part2 = part1 + (size_t)NB1 * 128;                  //    204,800 B
  float* stat1 = part2 + (size_t)NB2 * 32;                   //        512 B
  float* stat2 = stat1 + 128;                                //        128 B
  (void)ws_size; (void)in_sizes; (void)n_in; (void)out_size;

  k_qw<<<dim3(128), dim3(256), 0, stream>>>(q, W1, b1, qW, wsWT);
  k_gemm1<<<dim3(NB1), dim3(256), 0, stream>>>(q, hist, wsWT, qW, z1, part1);
  k_finalize<<<dim3(64), dim3(256), 0, stream>>>(part1, stat1, 64, 128, NB1, 1.f / (float)BT_);
  k_gemm2<<<dim3(NB2), dim3(256), 0, stream>>>(z1, W2, b2, al1, stat1, z2, part2);
  k_finalize<<<dim3(16), dim3(256), 0, stream>>>(part2, stat2, 16, 32, NB2, 1.f / (float)BT_);
  k_attn<<<dim3(B_), dim3(256), 0, stream>>>(hist, z2, len, al2, stat2, out);
}